// Round 8
// baseline (336.110 us; speedup 1.0000x reference)
//
#include <hip/hip_runtime.h>
#include <hip/hip_fp16.h>

typedef __attribute__((ext_vector_type(8))) short bf16x8;
typedef __attribute__((ext_vector_type(4))) float f32x4;

__device__ __forceinline__ f32x4 mfma16(bf16x8 a, bf16x8 b, f32x4 c) {
    return __builtin_amdgcn_mfma_f32_16x16x32_bf16(a, b, c, 0, 0, 0);
}

__device__ __forceinline__ unsigned short bf16_rte(float f) {
    unsigned int u = __float_as_uint(f);
    unsigned int r = (u + 0x7FFFu + ((u >> 16) & 1u)) >> 16;
    return (unsigned short)r;
}
__device__ __forceinline__ float bf16_f(unsigned short h) {
    return __uint_as_float(((unsigned int)h) << 16);
}

// split 8 fp16 values (bit-packed) into bf16 hi/lo (exact)
__device__ __forceinline__ void split8h(bf16x8 raw, bf16x8& hi, bf16x8& lo) {
#pragma unroll
    for (int j = 0; j < 8; ++j) {
        float f = __half2float(__ushort_as_half((unsigned short)raw[j]));
        unsigned short h = bf16_rte(f);
        hi[j] = (short)h;
        lo[j] = (short)bf16_rte(f - bf16_f(h));
    }
}

__device__ __forceinline__ void acc8(uint4 r, float4& A0, float4& A1) {
    float2 v0 = __half22float2(*(const __half2*)&r.x);
    float2 v1 = __half22float2(*(const __half2*)&r.y);
    float2 v2 = __half22float2(*(const __half2*)&r.z);
    float2 v3 = __half22float2(*(const __half2*)&r.w);
    A0.x += v0.x; A0.y += v0.y; A0.z += v1.x; A0.w += v1.y;
    A1.x += v2.x; A1.y += v2.y; A1.z += v3.x; A1.w += v3.y;
}

__device__ __forceinline__ void acc4(uint2 r, float4& A) {
    float2 v0 = __half22float2(*(const __half2*)&r.x);
    float2 v1 = __half22float2(*(const __half2*)&r.y);
    A.x += v0.x; A.y += v0.y; A.z += v1.x; A.w += v1.y;
}

#define MAXNB 1024

// ---------------- fused prep: wconv + xconv + bcount (bcnt pre-zeroed) ------
__global__ __launch_bounds__(256) void k_prep(
    const float* __restrict__ Wl1, const float* __restrict__ Wr1,
    const float* __restrict__ Wl2, const float* __restrict__ Wr2,
    unsigned short* __restrict__ w1ah, unsigned short* __restrict__ w1al,
    unsigned short* __restrict__ w1bh, unsigned short* __restrict__ w1bl,
    unsigned short* __restrict__ w2ah, unsigned short* __restrict__ w2al,
    unsigned short* __restrict__ w2bh, unsigned short* __restrict__ w2bl,
    const float* __restrict__ x, unsigned short* __restrict__ x16,
    const int* __restrict__ dst, int* __restrict__ bcnt,
    int E, int chunk, int xb, int nb, int total8) {
    __shared__ int hh[MAXNB];
    int b = blockIdx.x;
    int t = threadIdx.x;
    if (b < 192) {  // weight conversion: 64+64+32+32 blocks
        const float* W;
        unsigned short *hi, *lo;
        int F, e;
        if (b < 64)       { W = Wl1; hi = w1ah; lo = w1al; F = 128; e = b * 256 + t; }
        else if (b < 128) { W = Wr1; hi = w1bh; lo = w1bl; F = 128; e = (b - 64) * 256 + t; }
        else if (b < 160) { W = Wl2; hi = w2ah; lo = w2al; F = 64;  e = (b - 128) * 256 + t; }
        else              { W = Wr2; hi = w2bh; lo = w2bl; F = 64;  e = (b - 160) * 256 + t; }
        if (e >= 128 * F) return;
        int col = e >> 7, k = e & 127;
        float v = W[(size_t)k * F + col];
        unsigned short h = bf16_rte(v);
        hi[e] = h;
        lo[e] = bf16_rte(v - bf16_f(h));
    } else if (b < 192 + xb) {  // x fp32 -> fp16 table
        int i = (b - 192) * 256 + t;
        if (i >= total8) return;
        const float4* xp = (const float4*)x + (size_t)i * 2;
        float4 a = xp[0], bb = xp[1];
        bf16x8 o;
        o[0] = (short)__half_as_ushort(__float2half_rn(a.x));
        o[1] = (short)__half_as_ushort(__float2half_rn(a.y));
        o[2] = (short)__half_as_ushort(__float2half_rn(a.z));
        o[3] = (short)__half_as_ushort(__float2half_rn(a.w));
        o[4] = (short)__half_as_ushort(__float2half_rn(bb.x));
        o[5] = (short)__half_as_ushort(__float2half_rn(bb.y));
        o[6] = (short)__half_as_ushort(__float2half_rn(bb.z));
        o[7] = (short)__half_as_ushort(__float2half_rn(bb.w));
        *(bf16x8*)&x16[(size_t)i * 8] = o;
    } else {  // bucket count (two-level histogram)
        int cb = b - 192 - xb;
        for (int i = t; i < nb; i += 256) hh[i] = 0;
        __syncthreads();
        int base = cb * chunk;
        int end = min(base + chunk, E);
        for (int i = base + t; i < end; i += 256) atomicAdd(&hh[dst[i] >> 7], 1);
        __syncthreads();
        for (int i = t; i < nb; i += 256)
            if (hh[i]) atomicAdd(&bcnt[i], hh[i]);
    }
}

// ---------------- bucketed CSR build (proven) ------------

__global__ void k_bscan(const int* __restrict__ bcnt, int* __restrict__ boff,
                        int* __restrict__ bcur, int nb) {
    __shared__ int sh[1024];
    int t = threadIdx.x;
    int v = (t < nb) ? bcnt[t] : 0;
    sh[t] = v;
    __syncthreads();
    for (int off = 1; off < 1024; off <<= 1) {
        int u = (t >= off) ? sh[t - off] : 0;
        __syncthreads();
        sh[t] += u;
        __syncthreads();
    }
    if (t < nb) {
        int ex = sh[t] - v;
        boff[t] = ex;
        bcur[t] = ex;
    }
}

__global__ __launch_bounds__(256) void k_bscatter(
    const int* __restrict__ src, const int* __restrict__ dst,
    int* __restrict__ bcur, int2* __restrict__ pairs, int E, int chunk, int nb) {
    __shared__ int h[MAXNB];
    __shared__ int curs[MAXNB];
    int t = threadIdx.x;
    for (int i = t; i < nb; i += 256) h[i] = 0;
    __syncthreads();
    int base = blockIdx.x * chunk;
    int end = min(base + chunk, E);
    for (int i = base + t; i < end; i += 256) atomicAdd(&h[dst[i] >> 7], 1);
    __syncthreads();
    for (int i = t; i < nb; i += 256)
        curs[i] = h[i] ? atomicAdd(&bcur[i], h[i]) : 0;
    __syncthreads();
    for (int i = base + t; i < end; i += 256) {
        int d = dst[i];
        int p = atomicAdd(&curs[d >> 7], 1);
        pairs[p] = make_int2(d, src[i]);
    }
}

__global__ __launch_bounds__(256) void k_build(
    const int2* __restrict__ pairs, const int* __restrict__ boff,
    int* __restrict__ csr, int* __restrict__ start, int* __restrict__ deg,
    int n, int nb, int E) {
    __shared__ int scnt[128];
    __shared__ int soff[128];
    __shared__ int cur[128];
    int b = blockIdx.x;
    int t = threadIdx.x;
    int base = boff[b];
    int end = (b + 1 < nb) ? boff[b + 1] : E;
    if (t < 128) scnt[t] = 0;
    __syncthreads();
    for (int i = base + t; i < end; i += 256) {
        int2 e = pairs[i];
        atomicAdd(&scnt[e.x & 127], 1);
    }
    __syncthreads();
    if (t < 128) soff[t] = scnt[t];
    __syncthreads();
    for (int off = 1; off < 128; off <<= 1) {
        int val = 0;
        if (t < 128 && t >= off) val = soff[t - off];
        __syncthreads();
        if (t < 128) soff[t] += val;
        __syncthreads();
    }
    if (t < 128) {
        int c = scnt[t];
        int ex = soff[t] - c;
        int node = b * 128 + t;
        if (node < n) {
            start[node] = base + ex;
            deg[node] = c;
        }
        cur[t] = base + ex;
    }
    __syncthreads();
    for (int i = base + t; i < end; i += 256) {
        int2 e = pairs[i];
        int p = atomicAdd(&cur[e.x & 127], 1);
        csr[p] = e.y;
    }
}

#define SR 40

// ---------------- fused layer 1: gather-mean + dual GEMM --------------------
// Per 64-node block: phase 0 stages x16 (own rows) and runs x@Wr1 MFMA; then
// the gather-mean of the tile's neighbors runs IN-kernel (unroll-8: 8x16B rows
// in flight/lane -> 16 KB/CU at 2 blocks/CU, enough for the ~3.6 TB/s miss
// path per Little's law), writing bf16 hi/lo means directly into the freed LDS
// staging buffers; phase 1 runs xm@Wl1. The latency-bound GEMM work (only
// ~2.4 us/CU of real MFMA) hides under the bandwidth-bound gather instead of
// occupying its own ~55 us of wall-clock. xm16 is never materialized.
__global__ __launch_bounds__(256, 2) void fused1(
    const unsigned short* __restrict__ X,
    const int* __restrict__ csr, const int* __restrict__ start,
    const int* __restrict__ deg,
    const unsigned short* __restrict__ W0H, const unsigned short* __restrict__ W0L,
    const unsigned short* __restrict__ W1H, const unsigned short* __restrict__ W1L,
    const float* __restrict__ bias, unsigned short* __restrict__ dstH, int n) {
    constexpr int CT = 2;
    __shared__ unsigned short aHi[4][64 * SR], aLo[4][64 * SR];

    int t = threadIdx.x;
    int wv = t >> 6, l = t & 63, q = l >> 4, nl = l & 15;
    int wc = wv * 32;
    int node0 = blockIdx.x * 64;
    int sn = t >> 2, q4 = t & 3;
    int gn = min(node0 + sn, n - 1);

    // ---- phase 0 staging: x16 rows of own nodes, split to bf16 hi/lo ----
    {
        const unsigned short* p = X + (size_t)gn * 128 + q4 * 8;
        bf16x8 r[4];
#pragma unroll
        for (int c = 0; c < 4; ++c) r[c] = *(const bf16x8*)(p + c * 32);
        int base = sn * SR + q4 * 8;
#pragma unroll
        for (int c = 0; c < 4; ++c) {
            bf16x8 hi, lo;
            split8h(r[c], hi, lo);
            *(bf16x8*)&aHi[c][base] = hi;
            *(bf16x8*)&aLo[c][base] = lo;
        }
    }

    f32x4 acc[4][CT];
#pragma unroll
    for (int a = 0; a < 4; ++a)
#pragma unroll
        for (int b = 0; b < CT; ++b) acc[a][b] = (f32x4){0.f, 0.f, 0.f, 0.f};

    bf16x8 wh[2][CT], wl[2][CT];
#pragma unroll
    for (int uu = 0; uu < CT; ++uu) {
        int base = (wc + uu * 16 + nl) * 128 + q * 8;
        wh[0][uu] = *(const bf16x8*)&W0H[base];
        wl[0][uu] = *(const bf16x8*)&W0L[base];
    }
    __syncthreads();

    // ---- phase 0 MFMA: acc += x @ Wr1 ----
#pragma unroll
    for (int c = 0; c < 4; ++c) {
        if (c < 3) {
#pragma unroll
            for (int uu = 0; uu < CT; ++uu) {
                int base = (wc + uu * 16 + nl) * 128 + (c + 1) * 32 + q * 8;
                wh[(c + 1) & 1][uu] = *(const bf16x8*)&W0H[base];
                wl[(c + 1) & 1][uu] = *(const bf16x8*)&W0L[base];
            }
        }
        bf16x8 ah[4], al[4];
#pragma unroll
        for (int tt = 0; tt < 4; ++tt) {
            int off = (tt * 16 + nl) * SR + q * 8;
            ah[tt] = *(const bf16x8*)&aHi[c][off];
            al[tt] = *(const bf16x8*)&aLo[c][off];
        }
        int cb = c & 1;
#pragma unroll
        for (int tt = 0; tt < 4; ++tt)
#pragma unroll
            for (int uu = 0; uu < CT; ++uu) {
                f32x4 a = acc[tt][uu];
                a = mfma16(al[tt], wh[cb][uu], a);
                a = mfma16(ah[tt], wl[cb][uu], a);
                a = mfma16(ah[tt], wh[cb][uu], a);
                acc[tt][uu] = a;
            }
    }
    __syncthreads();  // phase-0 LDS reads done; buffers free for gather means

    // ---- gather-mean phase: wave wv covers local nodes [wv*16, wv*16+16) ---
    {
        int sub = l >> 4, fl = l & 15;
        int cch = fl >> 2, qq = fl & 3;
#pragma unroll 1
        for (int r4 = 0; r4 < 4; ++r4) {
            int nloc = wv * 16 + r4 * 4 + sub;
            int nc = min(node0 + nloc, n - 1);
            int s = start[nc], d = deg[nc];
            float4 A0 = {0.f, 0.f, 0.f, 0.f}, A1 = {0.f, 0.f, 0.f, 0.f};
            int j = 0;
            if (d >= 8) {
                int idx[8];
#pragma unroll
                for (int k = 0; k < 8; ++k) idx[k] = csr[s + k];
                for (; j + 16 <= d; j += 8) {
                    uint4 rr[8];
#pragma unroll
                    for (int k = 0; k < 8; ++k)
                        rr[k] = ((const uint4*)(X + (size_t)idx[k] * 128))[fl];
#pragma unroll
                    for (int k = 0; k < 8; ++k) idx[k] = csr[s + j + 8 + k];
#pragma unroll
                    for (int k = 0; k < 8; ++k) acc8(rr[k], A0, A1);
                }
                {
                    uint4 rr[8];
#pragma unroll
                    for (int k = 0; k < 8; ++k)
                        rr[k] = ((const uint4*)(X + (size_t)idx[k] * 128))[fl];
#pragma unroll
                    for (int k = 0; k < 8; ++k) acc8(rr[k], A0, A1);
                    j += 8;
                }
            }
            for (; j < d; ++j)
                acc8(((const uint4*)(X + (size_t)csr[s + j] * 128))[fl], A0, A1);
            float inv = 1.0f / (float)max(d, 1);
            float m[8] = {A0.x * inv, A0.y * inv, A0.z * inv, A0.w * inv,
                          A1.x * inv, A1.y * inv, A1.z * inv, A1.w * inv};
            bf16x8 hi, lo;
#pragma unroll
            for (int k = 0; k < 8; ++k) {
                unsigned short hh = bf16_rte(m[k]);
                hi[k] = (short)hh;
                lo[k] = (short)bf16_rte(m[k] - bf16_f(hh));
            }
            int base = nloc * SR + qq * 8;
            *(bf16x8*)&aHi[cch][base] = hi;
            *(bf16x8*)&aLo[cch][base] = lo;
        }
    }

    // W1 chunk-0 frags (L2-hot; loaded late to keep gather VGPR pressure low)
#pragma unroll
    for (int uu = 0; uu < CT; ++uu) {
        int base = (wc + uu * 16 + nl) * 128 + q * 8;
        wh[0][uu] = *(const bf16x8*)&W1H[base];
        wl[0][uu] = *(const bf16x8*)&W1L[base];
    }
    __syncthreads();  // gather means staged

    // ---- phase 1 MFMA: acc += xm @ Wl1 ----
#pragma unroll
    for (int c = 0; c < 4; ++c) {
        if (c < 3) {
#pragma unroll
            for (int uu = 0; uu < CT; ++uu) {
                int base = (wc + uu * 16 + nl) * 128 + (c + 1) * 32 + q * 8;
                wh[(c + 1) & 1][uu] = *(const bf16x8*)&W1H[base];
                wl[(c + 1) & 1][uu] = *(const bf16x8*)&W1L[base];
            }
        }
        bf16x8 ah[4], al[4];
#pragma unroll
        for (int tt = 0; tt < 4; ++tt) {
            int off = (tt * 16 + nl) * SR + q * 8;
            ah[tt] = *(const bf16x8*)&aHi[c][off];
            al[tt] = *(const bf16x8*)&aLo[c][off];
        }
        int cb = c & 1;
#pragma unroll
        for (int tt = 0; tt < 4; ++tt)
#pragma unroll
            for (int uu = 0; uu < CT; ++uu) {
                f32x4 a = acc[tt][uu];
                a = mfma16(al[tt], wh[cb][uu], a);
                a = mfma16(ah[tt], wl[cb][uu], a);
                a = mfma16(ah[tt], wh[cb][uu], a);
                acc[tt][uu] = a;
            }
    }
    __syncthreads();

    // ---- epilogue: bias + relu, LDS transpose, coalesced fp16 row stores ---
    unsigned short* tb = &aHi[0][0];  // 64 x 136 ushorts = 8704 B (fits)
#pragma unroll
    for (int uu = 0; uu < CT; ++uu) {
        int col = wc + uu * 16 + nl;
        float bv = bias[col];
#pragma unroll
        for (int tt = 0; tt < 4; ++tt)
#pragma unroll
            for (int r = 0; r < 4; ++r) {
                float vv = fmaxf(acc[tt][uu][r] + bv, 0.f);
                tb[(tt * 16 + q * 4 + r) * 136 + col] =
                    __half_as_ushort(__float2half_rn(vv));
            }
    }
    __syncthreads();
    int node = node0 + sn;
    if (node < n) {
        const unsigned short* sp = tb + sn * 136 + q4 * 32;
        unsigned short* dp = dstH + (size_t)node * 128 + q4 * 32;
#pragma unroll
        for (int i = 0; i < 4; ++i) *(bf16x8*)(dp + i * 8) = *(const bf16x8*)(sp + i * 8);
    }
}

// ---------------- layer-2 single-source dual-output GEMM (proven r7) --------
__global__ __launch_bounds__(256, 2) void gemm2d(
    const unsigned short* __restrict__ H,
    const unsigned short* __restrict__ WaH, const unsigned short* __restrict__ WaL,
    const unsigned short* __restrict__ WbH, const unsigned short* __restrict__ WbL,
    const float* __restrict__ bias, unsigned short* __restrict__ p16,
    float* __restrict__ outF, int n) {
    constexpr int CT = 2;
    __shared__ unsigned short aHi[4][64 * SR], aLo[4][64 * SR];

    int t = threadIdx.x;
    int wv = t >> 6, l = t & 63, q = l >> 4, nl = l & 15;
    int ysel = wv >> 1;
    int wc = (wv & 1) * 32;
    int node0 = blockIdx.x * 64;
    int sn = t >> 2, q4 = t & 3;
    int gn = min(node0 + sn, n - 1);
    const unsigned short* WH = ysel ? WbH : WaH;
    const unsigned short* WL = ysel ? WbL : WaL;

    {
        const unsigned short* p = H + (size_t)gn * 128 + q4 * 8;
        bf16x8 r[4];
#pragma unroll
        for (int c = 0; c < 4; ++c) r[c] = *(const bf16x8*)(p + c * 32);
        int base = sn * SR + q4 * 8;
#pragma unroll
        for (int c = 0; c < 4; ++c) {
            bf16x8 hi, lo;
            split8h(r[c], hi, lo);
            *(bf16x8*)&aHi[c][base] = hi;
            *(bf16x8*)&aLo[c][base] = lo;
        }
    }

    f32x4 acc[4][CT];
#pragma unroll
    for (int a = 0; a < 4; ++a)
#pragma unroll
        for (int b = 0; b < CT; ++b) acc[a][b] = (f32x4){0.f, 0.f, 0.f, 0.f};

    bf16x8 wh[2][CT], wl[2][CT];
#pragma unroll
    for (int uu = 0; uu < CT; ++uu) {
        int base = (wc + uu * 16 + nl) * 128 + q * 8;
        wh[0][uu] = *(const bf16x8*)&WH[base];
        wl[0][uu] = *(const bf16x8*)&WL[base];
    }
    __syncthreads();

#pragma unroll
    for (int c = 0; c < 4; ++c) {
        if (c < 3) {
#pragma unroll
            for (int uu = 0; uu < CT; ++uu) {
                int base = (wc + uu * 16 + nl) * 128 + (c + 1) * 32 + q * 8;
                wh[(c + 1) & 1][uu] = *(const bf16x8*)&WH[base];
                wl[(c + 1) & 1][uu] = *(const bf16x8*)&WL[base];
            }
        }
        bf16x8 ah[4], al[4];
#pragma unroll
        for (int tt = 0; tt < 4; ++tt) {
            int off = (tt * 16 + nl) * SR + q * 8;
            ah[tt] = *(const bf16x8*)&aHi[c][off];
            al[tt] = *(const bf16x8*)&aLo[c][off];
        }
        int cb = c & 1;
#pragma unroll
        for (int tt = 0; tt < 4; ++tt)
#pragma unroll
            for (int uu = 0; uu < CT; ++uu) {
                f32x4 a = acc[tt][uu];
                a = mfma16(al[tt], wh[cb][uu], a);
                a = mfma16(ah[tt], wl[cb][uu], a);
                a = mfma16(ah[tt], wh[cb][uu], a);
                acc[tt][uu] = a;
            }
    }
    __syncthreads();

    unsigned short* tbu = &aHi[0][0];
    float* tbf = (float*)&aLo[0][0];
#pragma unroll
    for (int uu = 0; uu < CT; ++uu) {
        int col = wc + uu * 16 + nl;
        if (ysel) {
            float bv = bias[col];
#pragma unroll
            for (int tt = 0; tt < 4; ++tt)
#pragma unroll
                for (int r = 0; r < 4; ++r)
                    tbf[(tt * 16 + q * 4 + r) * 68 + col] = acc[tt][uu][r] + bv;
        } else {
#pragma unroll
            for (int tt = 0; tt < 4; ++tt)
#pragma unroll
                for (int r = 0; r < 4; ++r)
                    tbu[(tt * 16 + q * 4 + r) * 72 + col] =
                        __half_as_ushort(__float2half_rn(acc[tt][uu][r]));
        }
    }
    __syncthreads();
    int node = node0 + sn;
    if (node < n) {
        const unsigned short* spu = tbu + sn * 72 + q4 * 16;
        unsigned short* dpu = p16 + (size_t)node * 64 + q4 * 16;
        *(bf16x8*)dpu = *(const bf16x8*)spu;
        *(bf16x8*)(dpu + 8) = *(const bf16x8*)(spu + 8);
        const float* spf = tbf + sn * 68 + q4 * 16;
        float* dpf = outF + (size_t)node * 64 + q4 * 16;
#pragma unroll
        for (int i = 0; i < 4; ++i) *(float4*)(dpf + i * 4) = *(const float4*)(spf + i * 4);
    }
}

// ---------------- layer-2 aggregation: gather p16, out += mean (unroll-8) ---
__global__ __launch_bounds__(256) void aggP(
    const unsigned short* __restrict__ tab, const int* __restrict__ csr,
    const int* __restrict__ start, const int* __restrict__ deg,
    float* __restrict__ outF, int n) {
    int gid = blockIdx.x * blockDim.x + threadIdx.x;
    int wave = gid >> 6, lane = gid & 63;
    int sub = lane >> 4, fl = lane & 15;
    int node = wave * 4 + sub;
    if (node >= n) return;
    int s = start[node], d = deg[node];
    float4 A = {0.f, 0.f, 0.f, 0.f};
    int j = 0;
    if (d >= 8) {
        int idx[8];
#pragma unroll
        for (int k = 0; k < 8; ++k) idx[k] = csr[s + k];
        for (; j + 16 <= d; j += 8) {
            uint2 rr[8];
#pragma unroll
            for (int k = 0; k < 8; ++k)
                rr[k] = ((const uint2*)(tab + (size_t)idx[k] * 64))[fl];
#pragma unroll
            for (int k = 0; k < 8; ++k) idx[k] = csr[s + j + 8 + k];
#pragma unroll
            for (int k = 0; k < 8; ++k) acc4(rr[k], A);
        }
        {
            uint2 rr[8];
#pragma unroll
            for (int k = 0; k < 8; ++k)
                rr[k] = ((const uint2*)(tab + (size_t)idx[k] * 64))[fl];
#pragma unroll
            for (int k = 0; k < 8; ++k) acc4(rr[k], A);
            j += 8;
        }
    }
    for (; j < d; ++j)
        acc4(((const uint2*)(tab + (size_t)csr[s + j] * 64))[fl], A);
    float inv = 1.0f / (float)max(d, 1);
    float* op = outF + (size_t)node * 64 + fl * 4;
    float4 cur = *(float4*)op;
    cur.x += A.x * inv;
    cur.y += A.y * inv;
    cur.z += A.z * inv;
    cur.w += A.w * inv;
    *(float4*)op = cur;
}

// ---------------- launch ----------------

extern "C" void kernel_launch(void* const* d_in, const int* in_sizes, int n_in,
                              void* d_out, int out_size, void* d_ws, size_t ws_size,
                              hipStream_t stream) {
    const float* x   = (const float*)d_in[0];
    const int*   ei  = (const int*)d_in[1];
    const float* Wl1 = (const float*)d_in[2];
    const float* Wr1 = (const float*)d_in[3];
    const float* b1  = (const float*)d_in[4];
    const float* Wl2 = (const float*)d_in[5];
    const float* Wr2 = (const float*)d_in[6];
    const float* b2  = (const float*)d_in[7];
    float* out = (float*)d_out;

    int Nn = in_sizes[0] / 128;
    int E  = in_sizes[1] / 2;
    const int* src = ei;
    const int* dst = ei + E;
    int nb = (Nn + 127) / 128;  // 782 <= MAXNB

    char* ws = (char*)d_ws;
    auto alloc = [&](size_t bytes) -> char* {
        char* pp = ws;
        ws += (bytes + 255) / 256 * 256;
        return pp;
    };
    int* bcnt   = (int*)alloc((size_t)nb * 4);
    int* boff   = (int*)alloc((size_t)nb * 4);
    int* bcur   = (int*)alloc((size_t)nb * 4);
    int* start  = (int*)alloc((size_t)Nn * 4);
    int* deg    = (int*)alloc((size_t)Nn * 4);
    int* csr    = (int*)alloc((size_t)E * 4);
    unsigned short* x16  = (unsigned short*)alloc((size_t)Nn * 128 * 2);
    unsigned short* h16  = (unsigned short*)alloc((size_t)Nn * 128 * 2);
    unsigned short* p16  = (unsigned short*)alloc((size_t)Nn * 64 * 2);
    unsigned short* w1ah = (unsigned short*)alloc(128 * 128 * 2);
    unsigned short* w1al = (unsigned short*)alloc(128 * 128 * 2);
    unsigned short* w1bh = (unsigned short*)alloc(128 * 128 * 2);
    unsigned short* w1bl = (unsigned short*)alloc(128 * 128 * 2);
    unsigned short* w2ah = (unsigned short*)alloc(64 * 128 * 2);
    unsigned short* w2al = (unsigned short*)alloc(64 * 128 * 2);
    unsigned short* w2bh = (unsigned short*)alloc(64 * 128 * 2);
    unsigned short* w2bl = (unsigned short*)alloc(64 * 128 * 2);
    // pairs (12.8 MB) aliases p16 (12.8 MB): consumed by k_build before
    // gemm2d writes p16
    int2* pairs = (int2*)p16;

    hipMemsetAsync(bcnt, 0, (size_t)nb * 4, stream);

    int total8 = Nn * 16;
    int xb = (total8 + 255) / 256;
    int chunk = (E + 255) / 256;
    k_prep<<<192 + xb + 256, 256, 0, stream>>>(
        Wl1, Wr1, Wl2, Wr2,
        w1ah, w1al, w1bh, w1bl, w2ah, w2al, w2bh, w2bl,
        x, x16, dst, bcnt, E, chunk, xb, nb, total8);

    k_bscan<<<1, 1024, 0, stream>>>(bcnt, boff, bcur, nb);
    k_bscatter<<<256, 256, 0, stream>>>(src, dst, bcur, pairs, E, chunk, nb);
    k_build<<<nb, 256, 0, stream>>>(pairs, boff, csr, start, deg, Nn, nb, E);

    int gb = (Nn + 63) / 64;
    int ga = (Nn + 15) / 16;
    // layer 1 (fused): h = relu(agg(x)@Wl1 + x@Wr1 + b1)
    fused1<<<gb, 256, 0, stream>>>(x16, csr, start, deg,
                                   w1bh, w1bl, w1ah, w1al, b1, h16, Nn);
    // layer 2: p = h@Wl2, out = h@Wr2 + b2; out += mean-agg(p)   [linearity]
    gemm2d<<<gb, 256, 0, stream>>>(h16, w2ah, w2al, w2bh, w2bl, b2, p16, out, Nn);
    aggP<<<ga, 256, 0, stream>>>(p16, csr, start, deg, out, Nn);
}

// Round 9
// 328.116 us; speedup vs baseline: 1.0244x; 1.0244x over previous
//
#include <hip/hip_runtime.h>
#include <hip/hip_fp16.h>

typedef __attribute__((ext_vector_type(8))) short bf16x8;
typedef __attribute__((ext_vector_type(4))) float f32x4;

__device__ __forceinline__ f32x4 mfma16(bf16x8 a, bf16x8 b, f32x4 c) {
    return __builtin_amdgcn_mfma_f32_16x16x32_bf16(a, b, c, 0, 0, 0);
}

__device__ __forceinline__ unsigned short bf16_rte(float f) {
    unsigned int u = __float_as_uint(f);
    unsigned int r = (u + 0x7FFFu + ((u >> 16) & 1u)) >> 16;
    return (unsigned short)r;
}
__device__ __forceinline__ float bf16_f(unsigned short h) {
    return __uint_as_float(((unsigned int)h) << 16);
}

// split 8 fp16 values (bit-packed) into bf16 hi/lo (exact)
__device__ __forceinline__ void split8h(bf16x8 raw, bf16x8& hi, bf16x8& lo) {
#pragma unroll
    for (int j = 0; j < 8; ++j) {
        float f = __half2float(__ushort_as_half((unsigned short)raw[j]));
        unsigned short h = bf16_rte(f);
        hi[j] = (short)h;
        lo[j] = (short)bf16_rte(f - bf16_f(h));
    }
}

__device__ __forceinline__ void acc8(uint4 r, float4& A0, float4& A1) {
    float2 v0 = __half22float2(*(const __half2*)&r.x);
    float2 v1 = __half22float2(*(const __half2*)&r.y);
    float2 v2 = __half22float2(*(const __half2*)&r.z);
    float2 v3 = __half22float2(*(const __half2*)&r.w);
    A0.x += v0.x; A0.y += v0.y; A0.z += v1.x; A0.w += v1.y;
    A1.x += v2.x; A1.y += v2.y; A1.z += v3.x; A1.w += v3.y;
}

__device__ __forceinline__ void acc4(uint2 r, float4& A) {
    float2 v0 = __half22float2(*(const __half2*)&r.x);
    float2 v1 = __half22float2(*(const __half2*)&r.y);
    A.x += v0.x; A.y += v0.y; A.z += v1.x; A.w += v1.y;
}

#define MAXNB 1024

// ---------------- fused prep: wconv + xconv + bcount (bcnt pre-zeroed) ------
__global__ __launch_bounds__(256) void k_prep(
    const float* __restrict__ Wl1, const float* __restrict__ Wr1,
    const float* __restrict__ Wl2, const float* __restrict__ Wr2,
    unsigned short* __restrict__ w1ah, unsigned short* __restrict__ w1al,
    unsigned short* __restrict__ w1bh, unsigned short* __restrict__ w1bl,
    unsigned short* __restrict__ w2ah, unsigned short* __restrict__ w2al,
    unsigned short* __restrict__ w2bh, unsigned short* __restrict__ w2bl,
    const float* __restrict__ x, unsigned short* __restrict__ x16,
    const int* __restrict__ dst, int* __restrict__ bcnt,
    int E, int chunk, int xb, int nb, int total8) {
    __shared__ int hh[MAXNB];
    int b = blockIdx.x;
    int t = threadIdx.x;
    if (b < 192) {  // weight conversion: 64+64+32+32 blocks
        const float* W;
        unsigned short *hi, *lo;
        int F, e;
        if (b < 64)       { W = Wl1; hi = w1ah; lo = w1al; F = 128; e = b * 256 + t; }
        else if (b < 128) { W = Wr1; hi = w1bh; lo = w1bl; F = 128; e = (b - 64) * 256 + t; }
        else if (b < 160) { W = Wl2; hi = w2ah; lo = w2al; F = 64;  e = (b - 128) * 256 + t; }
        else              { W = Wr2; hi = w2bh; lo = w2bl; F = 64;  e = (b - 160) * 256 + t; }
        if (e >= 128 * F) return;
        int col = e >> 7, k = e & 127;
        float v = W[(size_t)k * F + col];
        unsigned short h = bf16_rte(v);
        hi[e] = h;
        lo[e] = bf16_rte(v - bf16_f(h));
    } else if (b < 192 + xb) {  // x fp32 -> fp16 table
        int i = (b - 192) * 256 + t;
        if (i >= total8) return;
        const float4* xp = (const float4*)x + (size_t)i * 2;
        float4 a = xp[0], bb = xp[1];
        bf16x8 o;
        o[0] = (short)__half_as_ushort(__float2half_rn(a.x));
        o[1] = (short)__half_as_ushort(__float2half_rn(a.y));
        o[2] = (short)__half_as_ushort(__float2half_rn(a.z));
        o[3] = (short)__half_as_ushort(__float2half_rn(a.w));
        o[4] = (short)__half_as_ushort(__float2half_rn(bb.x));
        o[5] = (short)__half_as_ushort(__float2half_rn(bb.y));
        o[6] = (short)__half_as_ushort(__float2half_rn(bb.z));
        o[7] = (short)__half_as_ushort(__float2half_rn(bb.w));
        *(bf16x8*)&x16[(size_t)i * 8] = o;
    } else {  // bucket count (two-level histogram)
        int cb = b - 192 - xb;
        for (int i = t; i < nb; i += 256) hh[i] = 0;
        __syncthreads();
        int base = cb * chunk;
        int end = min(base + chunk, E);
        for (int i = base + t; i < end; i += 256) atomicAdd(&hh[dst[i] >> 7], 1);
        __syncthreads();
        for (int i = t; i < nb; i += 256)
            if (hh[i]) atomicAdd(&bcnt[i], hh[i]);
    }
}

// ---------------- bucketed CSR build (proven) ------------

__global__ void k_bscan(const int* __restrict__ bcnt, int* __restrict__ boff,
                        int* __restrict__ bcur, int nb) {
    __shared__ int sh[1024];
    int t = threadIdx.x;
    int v = (t < nb) ? bcnt[t] : 0;
    sh[t] = v;
    __syncthreads();
    for (int off = 1; off < 1024; off <<= 1) {
        int u = (t >= off) ? sh[t - off] : 0;
        __syncthreads();
        sh[t] += u;
        __syncthreads();
    }
    if (t < nb) {
        int ex = sh[t] - v;
        boff[t] = ex;
        bcur[t] = ex;
    }
}

__global__ __launch_bounds__(256) void k_bscatter(
    const int* __restrict__ src, const int* __restrict__ dst,
    int* __restrict__ bcur, int2* __restrict__ pairs, int E, int chunk, int nb) {
    __shared__ int h[MAXNB];
    __shared__ int curs[MAXNB];
    int t = threadIdx.x;
    for (int i = t; i < nb; i += 256) h[i] = 0;
    __syncthreads();
    int base = blockIdx.x * chunk;
    int end = min(base + chunk, E);
    for (int i = base + t; i < end; i += 256) atomicAdd(&h[dst[i] >> 7], 1);
    __syncthreads();
    for (int i = t; i < nb; i += 256)
        curs[i] = h[i] ? atomicAdd(&bcur[i], h[i]) : 0;
    __syncthreads();
    for (int i = base + t; i < end; i += 256) {
        int d = dst[i];
        int p = atomicAdd(&curs[d >> 7], 1);
        pairs[p] = make_int2(d, src[i]);
    }
}

__global__ __launch_bounds__(256) void k_build(
    const int2* __restrict__ pairs, const int* __restrict__ boff,
    int* __restrict__ csr, int* __restrict__ start, int* __restrict__ deg,
    int n, int nb, int E) {
    __shared__ int scnt[128];
    __shared__ int soff[128];
    __shared__ int cur[128];
    int b = blockIdx.x;
    int t = threadIdx.x;
    int base = boff[b];
    int end = (b + 1 < nb) ? boff[b + 1] : E;
    if (t < 128) scnt[t] = 0;
    __syncthreads();
    for (int i = base + t; i < end; i += 256) {
        int2 e = pairs[i];
        atomicAdd(&scnt[e.x & 127], 1);
    }
    __syncthreads();
    if (t < 128) soff[t] = scnt[t];
    __syncthreads();
    for (int off = 1; off < 128; off <<= 1) {
        int val = 0;
        if (t < 128 && t >= off) val = soff[t - off];
        __syncthreads();
        if (t < 128) soff[t] += val;
        __syncthreads();
    }
    if (t < 128) {
        int c = scnt[t];
        int ex = soff[t] - c;
        int node = b * 128 + t;
        if (node < n) {
            start[node] = base + ex;
            deg[node] = c;
        }
        cur[t] = base + ex;
    }
    __syncthreads();
    for (int i = base + t; i < end; i += 256) {
        int2 e = pairs[i];
        int p = atomicAdd(&cur[e.x & 127], 1);
        csr[p] = e.y;
    }
}

#define SR 40

// ---------------- mean aggregation over x16 (256 B rows, proven r6/r7) ------
__global__ __launch_bounds__(256) void aggF(
    const unsigned short* __restrict__ tab, const int* __restrict__ csr,
    const int* __restrict__ start, const int* __restrict__ deg,
    unsigned short* __restrict__ outm, int n) {
    int gid = blockIdx.x * blockDim.x + threadIdx.x;
    int wave = gid >> 6, lane = gid & 63;
    int sub = lane >> 4, fl = lane & 15;
    int node = wave * 4 + sub;
    if (node >= n) return;
    int s = start[node], d = deg[node];
    float4 A0 = {0.f, 0.f, 0.f, 0.f}, A1 = {0.f, 0.f, 0.f, 0.f};
    int j = 0;
    if (d >= 4) {
        int i0 = csr[s], i1 = csr[s + 1], i2 = csr[s + 2], i3 = csr[s + 3];
        for (; j + 8 <= d; j += 4) {
            int n0 = csr[s + j + 4], n1 = csr[s + j + 5];
            int n2 = csr[s + j + 6], n3 = csr[s + j + 7];
            uint4 r0 = ((const uint4*)(tab + (size_t)i0 * 128))[fl];
            uint4 r1 = ((const uint4*)(tab + (size_t)i1 * 128))[fl];
            uint4 r2 = ((const uint4*)(tab + (size_t)i2 * 128))[fl];
            uint4 r3 = ((const uint4*)(tab + (size_t)i3 * 128))[fl];
            acc8(r0, A0, A1); acc8(r1, A0, A1);
            acc8(r2, A0, A1); acc8(r3, A0, A1);
            i0 = n0; i1 = n1; i2 = n2; i3 = n3;
        }
        {
            uint4 r0 = ((const uint4*)(tab + (size_t)i0 * 128))[fl];
            uint4 r1 = ((const uint4*)(tab + (size_t)i1 * 128))[fl];
            uint4 r2 = ((const uint4*)(tab + (size_t)i2 * 128))[fl];
            uint4 r3 = ((const uint4*)(tab + (size_t)i3 * 128))[fl];
            acc8(r0, A0, A1); acc8(r1, A0, A1);
            acc8(r2, A0, A1); acc8(r3, A0, A1);
            j += 4;
        }
    }
    for (; j < d; ++j)
        acc8(((const uint4*)(tab + (size_t)csr[s + j] * 128))[fl], A0, A1);
    float inv = 1.0f / (float)max(d, 1);
    __half2 h0 = __floats2half2_rn(A0.x * inv, A0.y * inv);
    __half2 h1 = __floats2half2_rn(A0.z * inv, A0.w * inv);
    __half2 h2 = __floats2half2_rn(A1.x * inv, A1.y * inv);
    __half2 h3 = __floats2half2_rn(A1.z * inv, A1.w * inv);
    uint4 w;
    w.x = *(unsigned int*)&h0;
    w.y = *(unsigned int*)&h1;
    w.z = *(unsigned int*)&h2;
    w.w = *(unsigned int*)&h3;
    *(uint4*)&outm[(size_t)node * 128 + fl * 8] = w;
}

// ---------------- fused layer-1 + layer-2 GEMM ------------------------------
// Per 64-node block:
//   phase 0: stage x16, acc += x@Wr1          (r7 gemm1f, proven)
//   phase 1: stage xm16 (from regs), acc += xm@Wl1
//   h = relu(acc + b1) -> fp16 in LDS tb      (identical numerics to old h16)
//   phase 2: restage h (split8h from tb), p16 = h@Wl2, out = h@Wr2 + b2
//             (r7 gemm2d, proven, sourced from LDS instead of global)
// h16 never hits global: -25.6 MB write, -25.6 MB read, -1 launch, -1 full
// staging latency phase. gemm2d's tile = gemm1f's tile, so fusion is exact.
__global__ __launch_bounds__(256, 2) void fused12(
    const unsigned short* __restrict__ X, const unsigned short* __restrict__ XM,
    const unsigned short* __restrict__ W0H, const unsigned short* __restrict__ W0L,
    const unsigned short* __restrict__ W1H, const unsigned short* __restrict__ W1L,
    const float* __restrict__ b1,
    const unsigned short* __restrict__ W2aH, const unsigned short* __restrict__ W2aL,
    const unsigned short* __restrict__ W2bH, const unsigned short* __restrict__ W2bL,
    const float* __restrict__ b2,
    unsigned short* __restrict__ p16, float* __restrict__ outF, int n) {
    constexpr int CT = 2;
    __shared__ unsigned short aHi[4][64 * SR], aLo[4][64 * SR];

    int t = threadIdx.x;
    int wv = t >> 6, l = t & 63, q = l >> 4, nl = l & 15;
    int wc = wv * 32;
    int node0 = blockIdx.x * 64;
    int sn = t >> 2, q4 = t & 3;
    int gn = min(node0 + sn, n - 1);

    // xm row prefetch into regs
    bf16x8 s1r[4];
    {
        const unsigned short* p = XM + (size_t)gn * 128 + q4 * 8;
#pragma unroll
        for (int c = 0; c < 4; ++c) s1r[c] = *(const bf16x8*)(p + c * 32);
    }
    bf16x8 w1h0[CT], w1l0[CT];
#pragma unroll
    for (int uu = 0; uu < CT; ++uu) {
        int base = (wc + uu * 16 + nl) * 128 + q * 8;
        w1h0[uu] = *(const bf16x8*)&W1H[base];
        w1l0[uu] = *(const bf16x8*)&W1L[base];
    }

    // ---- phase 0 staging: x16 rows, split to bf16 hi/lo ----
    {
        const unsigned short* p = X + (size_t)gn * 128 + q4 * 8;
        bf16x8 r[4];
#pragma unroll
        for (int c = 0; c < 4; ++c) r[c] = *(const bf16x8*)(p + c * 32);
        int base = sn * SR + q4 * 8;
#pragma unroll
        for (int c = 0; c < 4; ++c) {
            bf16x8 hi, lo;
            split8h(r[c], hi, lo);
            *(bf16x8*)&aHi[c][base] = hi;
            *(bf16x8*)&aLo[c][base] = lo;
        }
    }

    f32x4 acc[4][CT];
#pragma unroll
    for (int a = 0; a < 4; ++a)
#pragma unroll
        for (int b = 0; b < CT; ++b) acc[a][b] = (f32x4){0.f, 0.f, 0.f, 0.f};

    bf16x8 wh[2][CT], wl[2][CT];
#pragma unroll
    for (int uu = 0; uu < CT; ++uu) {
        int base = (wc + uu * 16 + nl) * 128 + q * 8;
        wh[0][uu] = *(const bf16x8*)&W0H[base];
        wl[0][uu] = *(const bf16x8*)&W0L[base];
    }
    __syncthreads();

    // ---- phase 0 MFMA: acc += x @ Wr1 ----
#pragma unroll
    for (int c = 0; c < 4; ++c) {
        if (c < 3) {
#pragma unroll
            for (int uu = 0; uu < CT; ++uu) {
                int base = (wc + uu * 16 + nl) * 128 + (c + 1) * 32 + q * 8;
                wh[(c + 1) & 1][uu] = *(const bf16x8*)&W0H[base];
                wl[(c + 1) & 1][uu] = *(const bf16x8*)&W0L[base];
            }
        }
        bf16x8 ah[4], al[4];
#pragma unroll
        for (int tt = 0; tt < 4; ++tt) {
            int off = (tt * 16 + nl) * SR + q * 8;
            ah[tt] = *(const bf16x8*)&aHi[c][off];
            al[tt] = *(const bf16x8*)&aLo[c][off];
        }
        int cb = c & 1;
#pragma unroll
        for (int tt = 0; tt < 4; ++tt)
#pragma unroll
            for (int uu = 0; uu < CT; ++uu) {
                f32x4 a = acc[tt][uu];
                a = mfma16(al[tt], wh[cb][uu], a);
                a = mfma16(ah[tt], wl[cb][uu], a);
                a = mfma16(ah[tt], wh[cb][uu], a);
                acc[tt][uu] = a;
            }
    }
    __syncthreads();

    // ---- phase 1 staging: xm from regs ----
    {
        int base = sn * SR + q4 * 8;
#pragma unroll
        for (int c = 0; c < 4; ++c) {
            bf16x8 hi, lo;
            split8h(s1r[c], hi, lo);
            *(bf16x8*)&aHi[c][base] = hi;
            *(bf16x8*)&aLo[c][base] = lo;
        }
    }
#pragma unroll
    for (int uu = 0; uu < CT; ++uu) { wh[0][uu] = w1h0[uu]; wl[0][uu] = w1l0[uu]; }
    __syncthreads();

    // ---- phase 1 MFMA: acc += xm @ Wl1 ----
#pragma unroll
    for (int c = 0; c < 4; ++c) {
        if (c < 3) {
#pragma unroll
            for (int uu = 0; uu < CT; ++uu) {
                int base = (wc + uu * 16 + nl) * 128 + (c + 1) * 32 + q * 8;
                wh[(c + 1) & 1][uu] = *(const bf16x8*)&W1H[base];
                wl[(c + 1) & 1][uu] = *(const bf16x8*)&W1L[base];
            }
        }
        bf16x8 ah[4], al[4];
#pragma unroll
        for (int tt = 0; tt < 4; ++tt) {
            int off = (tt * 16 + nl) * SR + q * 8;
            ah[tt] = *(const bf16x8*)&aHi[c][off];
            al[tt] = *(const bf16x8*)&aLo[c][off];
        }
        int cb = c & 1;
#pragma unroll
        for (int tt = 0; tt < 4; ++tt)
#pragma unroll
            for (int uu = 0; uu < CT; ++uu) {
                f32x4 a = acc[tt][uu];
                a = mfma16(al[tt], wh[cb][uu], a);
                a = mfma16(ah[tt], wl[cb][uu], a);
                a = mfma16(ah[tt], wh[cb][uu], a);
                acc[tt][uu] = a;
            }
    }
    __syncthreads();

    // ---- h = relu(acc + b1) -> fp16 transpose buffer (node-row layout) ----
    unsigned short* tb = &aHi[0][0];  // 64 x 136 ushorts = 17408 B (fits)
#pragma unroll
    for (int uu = 0; uu < CT; ++uu) {
        int col = wc + uu * 16 + nl;
        float bv = b1[col];
#pragma unroll
        for (int tt = 0; tt < 4; ++tt)
#pragma unroll
            for (int r = 0; r < 4; ++r) {
                float vv = fmaxf(acc[tt][uu][r] + bv, 0.f);
                tb[(tt * 16 + q * 4 + r) * 136 + col] =
                    __half_as_ushort(__float2half_rn(vv));
            }
    }
    __syncthreads();

    // ---- read own h rows from tb into regs ----
    bf16x8 hreg[4];
    {
        const unsigned short* sp = tb + sn * 136 + q4 * 8;
#pragma unroll
        for (int c = 0; c < 4; ++c) hreg[c] = *(const bf16x8*)(sp + c * 32);
    }
    __syncthreads();  // tb reads done; aHi/aLo free for h staging

    // ---- phase 2 staging: h split to bf16 hi/lo ----
    {
        int base = sn * SR + q4 * 8;
#pragma unroll
        for (int c = 0; c < 4; ++c) {
            bf16x8 hi, lo;
            split8h(hreg[c], hi, lo);
            *(bf16x8*)&aHi[c][base] = hi;
            *(bf16x8*)&aLo[c][base] = lo;
        }
    }
    // W2 frags: waves 0,1 -> Wl2 (p16); waves 2,3 -> Wr2 (out)
    int ysel = wv >> 1;
    int wc2 = (wv & 1) * 32;
    const unsigned short* W2H = ysel ? W2bH : W2aH;
    const unsigned short* W2L = ysel ? W2bL : W2aL;
#pragma unroll
    for (int uu = 0; uu < CT; ++uu) {
        int base = (wc2 + uu * 16 + nl) * 128 + q * 8;
        wh[0][uu] = *(const bf16x8*)&W2H[base];
        wl[0][uu] = *(const bf16x8*)&W2L[base];
    }
#pragma unroll
    for (int a = 0; a < 4; ++a)
#pragma unroll
        for (int b = 0; b < CT; ++b) acc[a][b] = (f32x4){0.f, 0.f, 0.f, 0.f};
    __syncthreads();

    // ---- phase 2 MFMA: acc = h @ W2[ysel] ----
#pragma unroll
    for (int c = 0; c < 4; ++c) {
        if (c < 3) {
#pragma unroll
            for (int uu = 0; uu < CT; ++uu) {
                int base = (wc2 + uu * 16 + nl) * 128 + (c + 1) * 32 + q * 8;
                wh[(c + 1) & 1][uu] = *(const bf16x8*)&W2H[base];
                wl[(c + 1) & 1][uu] = *(const bf16x8*)&W2L[base];
            }
        }
        bf16x8 ah[4], al[4];
#pragma unroll
        for (int tt = 0; tt < 4; ++tt) {
            int off = (tt * 16 + nl) * SR + q * 8;
            ah[tt] = *(const bf16x8*)&aHi[c][off];
            al[tt] = *(const bf16x8*)&aLo[c][off];
        }
        int cb = c & 1;
#pragma unroll
        for (int tt = 0; tt < 4; ++tt)
#pragma unroll
            for (int uu = 0; uu < CT; ++uu) {
                f32x4 a = acc[tt][uu];
                a = mfma16(al[tt], wh[cb][uu], a);
                a = mfma16(ah[tt], wl[cb][uu], a);
                a = mfma16(ah[tt], wh[cb][uu], a);
                acc[tt][uu] = a;
            }
    }
    __syncthreads();

    // ---- epilogue 2: p16 (fp16) via aHi, out (fp32, +b2) via aLo ----
    unsigned short* tbu = &aHi[0][0];  // 64 x 72 ushorts
    float* tbf = (float*)&aLo[0][0];   // 64 x 68 floats
#pragma unroll
    for (int uu = 0; uu < CT; ++uu) {
        int col = wc2 + uu * 16 + nl;
        if (ysel) {
            float bv = b2[col];
#pragma unroll
            for (int tt = 0; tt < 4; ++tt)
#pragma unroll
                for (int r = 0; r < 4; ++r)
                    tbf[(tt * 16 + q * 4 + r) * 68 + col] = acc[tt][uu][r] + bv;
        } else {
#pragma unroll
            for (int tt = 0; tt < 4; ++tt)
#pragma unroll
                for (int r = 0; r < 4; ++r)
                    tbu[(tt * 16 + q * 4 + r) * 72 + col] =
                        __half_as_ushort(__float2half_rn(acc[tt][uu][r]));
        }
    }
    __syncthreads();
    int node = node0 + sn;
    if (node < n) {
        const unsigned short* spu = tbu + sn * 72 + q4 * 16;
        unsigned short* dpu = p16 + (size_t)node * 64 + q4 * 16;
        *(bf16x8*)dpu = *(const bf16x8*)spu;
        *(bf16x8*)(dpu + 8) = *(const bf16x8*)(spu + 8);
        const float* spf = tbf + sn * 68 + q4 * 16;
        float* dpf = outF + (size_t)node * 64 + q4 * 16;
#pragma unroll
        for (int i = 0; i < 4; ++i) *(float4*)(dpf + i * 4) = *(const float4*)(spf + i * 4);
    }
}

// ---------------- layer-2 aggregation: gather p16, out += mean (unroll-8) ---
__global__ __launch_bounds__(256) void aggP(
    const unsigned short* __restrict__ tab, const int* __restrict__ csr,
    const int* __restrict__ start, const int* __restrict__ deg,
    float* __restrict__ outF, int n) {
    int gid = blockIdx.x * blockDim.x + threadIdx.x;
    int wave = gid >> 6, lane = gid & 63;
    int sub = lane >> 4, fl = lane & 15;
    int node = wave * 4 + sub;
    if (node >= n) return;
    int s = start[node], d = deg[node];
    float4 A = {0.f, 0.f, 0.f, 0.f};
    int j = 0;
    if (d >= 8) {
        int idx[8];
#pragma unroll
        for (int k = 0; k < 8; ++k) idx[k] = csr[s + k];
        for (; j + 16 <= d; j += 8) {
            uint2 rr[8];
#pragma unroll
            for (int k = 0; k < 8; ++k)
                rr[k] = ((const uint2*)(tab + (size_t)idx[k] * 64))[fl];
#pragma unroll
            for (int k = 0; k < 8; ++k) idx[k] = csr[s + j + 8 + k];
#pragma unroll
            for (int k = 0; k < 8; ++k) acc4(rr[k], A);
        }
        {
            uint2 rr[8];
#pragma unroll
            for (int k = 0; k < 8; ++k)
                rr[k] = ((const uint2*)(tab + (size_t)idx[k] * 64))[fl];
#pragma unroll
            for (int k = 0; k < 8; ++k) acc4(rr[k], A);
            j += 8;
        }
    }
    for (; j < d; ++j)
        acc4(((const uint2*)(tab + (size_t)csr[s + j] * 64))[fl], A);
    float inv = 1.0f / (float)max(d, 1);
    float* op = outF + (size_t)node * 64 + fl * 4;
    float4 cur = *(float4*)op;
    cur.x += A.x * inv;
    cur.y += A.y * inv;
    cur.z += A.z * inv;
    cur.w += A.w * inv;
    *(float4*)op = cur;
}

// ---------------- launch ----------------

extern "C" void kernel_launch(void* const* d_in, const int* in_sizes, int n_in,
                              void* d_out, int out_size, void* d_ws, size_t ws_size,
                              hipStream_t stream) {
    const float* x   = (const float*)d_in[0];
    const int*   ei  = (const int*)d_in[1];
    const float* Wl1 = (const float*)d_in[2];
    const float* Wr1 = (const float*)d_in[3];
    const float* b1  = (const float*)d_in[4];
    const float* Wl2 = (const float*)d_in[5];
    const float* Wr2 = (const float*)d_in[6];
    const float* b2  = (const float*)d_in[7];
    float* out = (float*)d_out;

    int Nn = in_sizes[0] / 128;
    int E  = in_sizes[1] / 2;
    const int* src = ei;
    const int* dst = ei + E;
    int nb = (Nn + 127) / 128;  // 782 <= MAXNB

    char* ws = (char*)d_ws;
    auto alloc = [&](size_t bytes) -> char* {
        char* pp = ws;
        ws += (bytes + 255) / 256 * 256;
        return pp;
    };
    int* bcnt   = (int*)alloc((size_t)nb * 4);
    int* boff   = (int*)alloc((size_t)nb * 4);
    int* bcur   = (int*)alloc((size_t)nb * 4);
    int* start  = (int*)alloc((size_t)Nn * 4);
    int* deg    = (int*)alloc((size_t)Nn * 4);
    int* csr    = (int*)alloc((size_t)E * 4);
    unsigned short* x16  = (unsigned short*)alloc((size_t)Nn * 128 * 2);
    unsigned short* xm16 = (unsigned short*)alloc((size_t)Nn * 128 * 2);
    unsigned short* p16  = (unsigned short*)alloc((size_t)Nn * 64 * 2);
    unsigned short* w1ah = (unsigned short*)alloc(128 * 128 * 2);
    unsigned short* w1al = (unsigned short*)alloc(128 * 128 * 2);
    unsigned short* w1bh = (unsigned short*)alloc(128 * 128 * 2);
    unsigned short* w1bl = (unsigned short*)alloc(128 * 128 * 2);
    unsigned short* w2ah = (unsigned short*)alloc(64 * 128 * 2);
    unsigned short* w2al = (unsigned short*)alloc(64 * 128 * 2);
    unsigned short* w2bh = (unsigned short*)alloc(64 * 128 * 2);
    unsigned short* w2bl = (unsigned short*)alloc(64 * 128 * 2);
    // pairs (12.8 MB) aliases p16 (12.8 MB): consumed by k_build before
    // fused12 writes p16
    int2* pairs = (int2*)p16;

    hipMemsetAsync(bcnt, 0, (size_t)nb * 4, stream);

    int total8 = Nn * 16;
    int xb = (total8 + 255) / 256;
    int chunk = (E + 255) / 256;
    k_prep<<<192 + xb + 256, 256, 0, stream>>>(
        Wl1, Wr1, Wl2, Wr2,
        w1ah, w1al, w1bh, w1bl, w2ah, w2al, w2bh, w2bl,
        x, x16, dst, bcnt, E, chunk, xb, nb, total8);

    k_bscan<<<1, 1024, 0, stream>>>(bcnt, boff, bcur, nb);
    k_bscatter<<<256, 256, 0, stream>>>(src, dst, bcur, pairs, E, chunk, nb);
    k_build<<<nb, 256, 0, stream>>>(pairs, boff, csr, start, deg, Nn, nb, E);

    int gb = (Nn + 63) / 64;
    int ga = (Nn + 15) / 16;
    // layer 1 gather: xm = mean-agg(x)      [full-occupancy, proven]
    aggF<<<ga, 256, 0, stream>>>(x16, csr, start, deg, xm16, Nn);
    // fused layers: h = relu(xm@Wl1 + x@Wr1 + b1) in-LDS;
    //               p = h@Wl2, out = h@Wr2 + b2
    fused12<<<gb, 256, 0, stream>>>(x16, xm16,
                                    w1bh, w1bl, w1ah, w1al, b1,
                                    w2ah, w2al, w2bh, w2bl, b2,
                                    p16, out, Nn);
    // layer 2 gather: out += mean-agg(p)    [linearity]
    aggP<<<ga, 256, 0, stream>>>(p16, csr, start, deg, out, Nn);
}